// Round 7
// baseline (3618.240 us; speedup 1.0000x reference)
//
#include <hip/hip_runtime.h>
#include <hip/hip_cooperative_groups.h>

namespace cg = cooperative_groups;

typedef __attribute__((ext_vector_type(4))) float f32x4;
typedef __attribute__((ext_vector_type(4))) int   i32x4;
typedef __attribute__((ext_vector_type(8))) short s16x8;

#define MFMA16(a, b, c)  __builtin_amdgcn_mfma_f32_16x16x32_bf16((a), (b), (c), 0, 0, 0)
#define MFMAI8(a, b, c)  __builtin_amdgcn_mfma_i32_16x16x64_i8((a), (b), (c), 0, 0, 0)

#define QINV (1.0f / 252.0f)
#define SPSZ 2097152   // one spike buffer: 2048 rows x 1024 cols i8

// ---------- bf16 helpers (RNE) ----------
__device__ inline unsigned short f2bf(float f) {
    unsigned int u = __float_as_uint(f);
    return (unsigned short)((u + 0x7FFFu + ((u >> 16) & 1u)) >> 16);
}
__device__ inline float bf2f(unsigned short b) {
    return __uint_as_float(((unsigned int)b) << 16);
}

// ---------- pack W [K][1024] f32 -> THREE bf16 levels (for W_in path) ----------
__global__ __launch_bounds__(256) void k_pack3(const float* __restrict__ W,
                                               unsigned short* __restrict__ L1,
                                               unsigned short* __restrict__ L2,
                                               unsigned short* __restrict__ L3,
                                               int K) {
    int idx = blockIdx.x * 256 + threadIdx.x;
    if (idx >= K * 1024) return;
    int k = idx >> 10;
    int n = idx & 1023;
    float x = W[idx];
    unsigned short h1 = f2bf(x);  float r1 = x - bf2f(h1);
    unsigned short h2 = f2bf(r1); float r2 = r1 - bf2f(h2);
    unsigned short h3 = f2bf(r2);
    size_t o = ((size_t)(k >> 5) << 15) + ((size_t)n << 5) + (k & 31);
    L1[o] = h1; L2[o] = h2; L3[o] = h3;
}

// ---------- per-column max|W_rec| -> t1[n] = max/126 ----------
__global__ __launch_bounds__(256) void k_colmax(const float* __restrict__ W,
                                                float* __restrict__ t1) {
    __shared__ float red[256];
    int n = blockIdx.x;
    float m = 0.f;
    for (int k = threadIdx.x; k < 1024; k += 256)
        m = fmaxf(m, fabsf(W[(size_t)k * 1024 + n]));
    red[threadIdx.x] = m;
    __syncthreads();
    for (int s = 128; s > 0; s >>= 1) {
        if (threadIdx.x < s) red[threadIdx.x] = fmaxf(red[threadIdx.x], red[threadIdx.x + s]);
        __syncthreads();
    }
    if (threadIdx.x == 0) t1[n] = fmaxf(red[0], 1e-30f) * (1.0f / 126.0f);
}

// ---------- pack W_rec -> 3 i8 digits, interleaved [kt][n][lvl][64] ----------
__global__ __launch_bounds__(256) void k_packq(const float* __restrict__ W,
                                               const float* __restrict__ t1a,
                                               signed char* __restrict__ Q) {
    int idx = blockIdx.x * 256 + threadIdx.x;   // k*1024 + n
    int k = idx >> 10;
    int n = idx & 1023;
    float x = W[idx];
    float T1 = t1a[n];
    float T2 = T1 * QINV;
    float T3 = T2 * QINV;
    float q1 = rintf(x / T1);  float r1 = fmaf(-q1, T1, x);
    float q2 = rintf(r1 / T2); float r2 = fmaf(-q2, T2, r1);
    float q3 = rintf(r2 / T3);
    size_t o = ((size_t)((k >> 6) * 1024 + n)) * 192 + (k & 63);
    Q[o]       = (signed char)(int)q1;
    Q[o + 64]  = (signed char)(int)q2;
    Q[o + 128] = (signed char)(int)q3;
}

// ---------- cooperative main: 256 blocks x 512 thr; pair (2p,2p+1) = rows
// 16p..16p+16, block half h owns cols h*512..h*512+512. Spikes exchanged via
// global dbuf + grid sync each step. ----------
#define FSTR 770
__global__ __launch_bounds__(512, 2) void k_main(const float* __restrict__ fused,
                                                 const unsigned short* __restrict__ Wi1,
                                                 const unsigned short* __restrict__ Wi2,
                                                 const unsigned short* __restrict__ Wi3,
                                                 const float* __restrict__ b_in,
                                                 const signed char* __restrict__ WrQ,
                                                 const float* __restrict__ t1a,
                                                 const float* __restrict__ b_rec,
                                                 const float* __restrict__ rdec,
                                                 const float* __restrict__ rfrq,
                                                 const float* __restrict__ W_out,
                                                 const float* __restrict__ b_out,
                                                 char* __restrict__ spk,
                                                 float* __restrict__ out) {
    // LDS: [0,49280) fused tile f32[16][770] (phases A/B); [0,16384) A spike
    // tile i8[16][1024] XOR-swizzled (phase C); params @53248 (3 x 2KB).
    __shared__ __align__(16) char smem[59392];
    cg::grid_group grid = cg::this_grid();
    const int tid = threadIdx.x;
    const int w = tid >> 6, lane = tid & 63;
    const int llo = lane & 15, lhi = lane >> 4;
    const int bid = blockIdx.x;
    const int half = bid & 1;
    const int r0 = (bid >> 1) * 16;
    const int halfbase = half * 512;

    float* ldsDec = (float*)(smem + 53248);
    float* ldsFrq = (float*)(smem + 53248 + 2048);
    float* ldsT1  = (float*)(smem + 53248 + 4096);

    float brc[4];
#pragma unroll
    for (int nt = 0; nt < 4; ++nt) {
        int lc = w * 64 + nt * 16 + llo;
        int c = halfbase + lc;
        ldsDec[lc] = (float)(0.55 + 0.4 / (1.0 + exp(-(double)rdec[c])));
        ldsFrq[lc] = (float)(0.10 + 0.9 / (1.0 + exp(-(double)rfrq[c])));
        ldsT1[lc]  = t1a[c];
        brc[nt] = b_rec[c];
    }

    // ---- phase A: stage fused[r0:r0+16][0:768] into LDS ----
    float* fl = (float*)smem;
    for (int i = tid; i < 16 * 768; i += 512) {
        int rr = i / 768, cc = i - rr * 768;
        fl[rr * FSTR + cc] = fused[(size_t)(r0 + rr) * 768 + cc];
    }
    __syncthreads();

    // ---- phase B: base = fused @ W_in + b_in (3x3-level bf16, 6 passes) ----
    f32x4 bacc[4] = {};
    for (int kt = 0; kt < 24; ++kt) {
        const float* ap = fl + llo * FSTR + kt * 32 + lhi * 8;
        s16x8 a1v, a2v, a3v;
#pragma unroll
        for (int j = 0; j < 8; ++j) {
            float x = ap[j];
            unsigned short h1 = f2bf(x);  float r1 = x - bf2f(h1);
            unsigned short h2 = f2bf(r1); float r2 = r1 - bf2f(h2);
            a1v[j] = (short)h1; a2v[j] = (short)h2; a3v[j] = (short)f2bf(r2);
        }
#pragma unroll
        for (int nt = 0; nt < 4; ++nt) {
            int c = halfbase + w * 64 + nt * 16 + llo;
            size_t boff = ((size_t)(kt * 1024 + c) << 5) + lhi * 8;
            s16x8 b1 = *(const s16x8*)&Wi1[boff];
            s16x8 b2 = *(const s16x8*)&Wi2[boff];
            s16x8 b3 = *(const s16x8*)&Wi3[boff];
            bacc[nt] = MFMA16(a1v, b1, bacc[nt]);
            bacc[nt] = MFMA16(a1v, b2, bacc[nt]);
            bacc[nt] = MFMA16(a2v, b1, bacc[nt]);
            bacc[nt] = MFMA16(a2v, b2, bacc[nt]);
            bacc[nt] = MFMA16(a1v, b3, bacc[nt]);
            bacc[nt] = MFMA16(a3v, b1, bacc[nt]);
        }
    }
    // base2 = base + b_rec; inline step t=0; write spikes(0) to global buf0
    float base2[4][4];
    float mem[4][4], res[4][4];
    unsigned int pooled_pk[4] = {0, 0, 0, 0};
#pragma unroll
    for (int nt = 0; nt < 4; ++nt) {
        int c = halfbase + w * 64 + nt * 16 + llo;
        float bb = b_in[c];
#pragma unroll
        for (int fr = 0; fr < 4; ++fr) {
            int row = lhi * 4 + fr;
            float b0 = __fadd_rn(bacc[nt][fr], bb);
            base2[nt][fr] = __fadd_rn(b0, brc[nt]);
            float m_ = __fadd_rn(0.f, b0);
            int s = (m_ > 1.0f) ? 1 : 0;
            res[nt][fr] = 0.f;
            mem[nt][fr] = __fadd_rn(m_, -(float)s);
            pooled_pk[nt] += (unsigned int)s << (8 * fr);
            spk[(size_t)(r0 + row) * 1024 + c] = (char)s;
        }
    }
    __threadfence();
    grid.sync();

    // ---- phase C: steps 1..31 ----
    const int ax = (llo & 7) << 4;
    const signed char* bp0 = WrQ + ((size_t)(halfbase + w * 64 + llo)) * 192 + lhi * 16;
    for (int t = 1; t < 32; ++t) {
        // stage spikes(t-1) rows r0..r0+16 (all 1024 cols) -> LDS, XOR-swizzled
        {
            const char* gsp = spk + ((t - 1) & 1) * SPSZ + (size_t)r0 * 1024;
            int byteoff = tid * 32;
            int row = byteoff >> 10, col = byteoff & 1023;
            i32x4 v0 = *(const i32x4*)(gsp + byteoff);
            i32x4 v1 = *(const i32x4*)(gsp + byteoff + 16);
            int sw = (row & 7) << 4;
            *(i32x4*)(smem + ((row * 1024 + col) ^ sw)) = v0;
            *(i32x4*)(smem + ((row * 1024 + col + 16) ^ sw)) = v1;
        }
        __syncthreads();

        // kt loop, 2-deep register pipeline on the 12 B-fragments
        i32x4 q1a[4] = {}, q2a[4] = {}, q3a[4] = {};
        {
            i32x4 Bv[2][12];
#pragma unroll
            for (int nt = 0; nt < 4; ++nt) {
                const signed char* b = bp0 + nt * 3072;
                Bv[0][nt * 3 + 0] = *(const i32x4*)(b);
                Bv[0][nt * 3 + 1] = *(const i32x4*)(b + 64);
                Bv[0][nt * 3 + 2] = *(const i32x4*)(b + 128);
            }
#pragma unroll 2
            for (int kt = 0; kt < 16; ++kt) {
                const int cur = kt & 1, nxt = cur ^ 1;
                if (kt < 15) {
                    const signed char* bq = bp0 + (size_t)(kt + 1) * 196608;
#pragma unroll
                    for (int nt = 0; nt < 4; ++nt) {
                        const signed char* b = bq + nt * 3072;
                        Bv[nxt][nt * 3 + 0] = *(const i32x4*)(b);
                        Bv[nxt][nt * 3 + 1] = *(const i32x4*)(b + 64);
                        Bv[nxt][nt * 3 + 2] = *(const i32x4*)(b + 128);
                    }
                }
                i32x4 A = *(const i32x4*)(smem + (llo * 1024 + ((kt * 64 + lhi * 16) ^ ax)));
#pragma unroll
                for (int nt = 0; nt < 4; ++nt) {
                    q1a[nt] = MFMAI8(A, Bv[cur][nt * 3 + 0], q1a[nt]);
                    q2a[nt] = MFMAI8(A, Bv[cur][nt * 3 + 1], q2a[nt]);
                    q3a[nt] = MFMAI8(A, Bv[cur][nt * 3 + 2], q3a[nt]);
                }
            }
        }

        // state update + spike write to global buf[t&1]
        char* gw = spk + (t & 1) * SPSZ;
#pragma unroll
        for (int nt = 0; nt < 4; ++nt) {
            int lc = w * 64 + nt * 16 + llo;
            int c = halfbase + lc;
            float dcc = ldsDec[lc], fqc = ldsFrq[lc], t1c = ldsT1[lc];
#pragma unroll
            for (int fr = 0; fr < 4; ++fr) {
                int row = lhi * 4 + fr;
                float s3 = (float)q3a[nt][fr];
                float s2 = fmaf(s3, QINV, (float)q2a[nt][fr]);
                float rec = __fmul_rn(fmaf(s2, QINV, (float)q1a[nt][fr]), t1c);
                float drive = __fadd_rn(base2[nt][fr], rec);
                float rnew = __fadd_rn(__fmul_rn(dcc, res[nt][fr]),
                                       __fmul_rn(fqc, mem[nt][fr]));
                float tt = __fadd_rn(__fmul_rn(dcc, mem[nt][fr]), drive);
                float m_ = __fadd_rn(tt, -rnew);
                int s = (m_ > 1.0f) ? 1 : 0;
                res[nt][fr] = rnew;
                mem[nt][fr] = __fadd_rn(m_, -(float)s);
                pooled_pk[nt] += (unsigned int)s << (8 * fr);
                gw[(size_t)(r0 + row) * 1024 + c] = (char)s;
            }
        }
        if (t == 31) {
            // spikes(30) consumed; buf0 is dead -> write pooled counts there
            unsigned char* gc = (unsigned char*)spk;
#pragma unroll
            for (int nt = 0; nt < 4; ++nt) {
                int c = halfbase + w * 64 + nt * 16 + llo;
#pragma unroll
                for (int fr = 0; fr < 4; ++fr)
                    gc[(size_t)(r0 + lhi * 4 + fr) * 1024 + c] =
                        (unsigned char)((pooled_pk[nt] >> (8 * fr)) & 255u);
            }
        }
        __threadfence();
        grid.sync();
    }

    // ---- phase D: even block of each pair does out = pooled/32 @ W_out + b_out ----
    if (!half && tid < 256) {
        int row = tid >> 4, o = tid & 15;
        const unsigned char* cnt = (const unsigned char*)spk + (size_t)(r0 + row) * 1024;
        double s = 0.0;
        for (int h = 0; h < 1024; ++h)
            s += (double)((float)cnt[h] * 0.03125f) * (double)W_out[h * 16 + o];
        out[(size_t)(r0 + row) * 16 + o] = __fadd_rn((float)s, b_out[o]);
    }
}

extern "C" void kernel_launch(void* const* d_in, const int* in_sizes, int n_in,
                              void* d_out, int out_size, void* d_ws, size_t ws_size,
                              hipStream_t stream) {
    const float* fused = (const float*)d_in[0];
    const float* W_in  = (const float*)d_in[1];
    const float* b_in  = (const float*)d_in[2];
    const float* W_rec = (const float*)d_in[3];
    const float* b_rec = (const float*)d_in[4];
    const float* W_out = (const float*)d_in[5];
    const float* b_out = (const float*)d_in[6];
    const float* rdec  = (const float*)d_in[7];
    const float* rfrq  = (const float*)d_in[8];

    // ws: WrQ 3MB | t1 4KB | Wi1/2/3 4.5MB | spikes 4MB  (total ~11.8MB)
    char* ws = (char*)d_ws;
    signed char*    WrQ = (signed char*)(ws);
    float*          t1a = (float*)(ws + (3u << 20));
    unsigned short* Wi1 = (unsigned short*)(ws + (3u << 20) + (1u << 18));
    unsigned short* Wi2 = (unsigned short*)(ws + (3u << 20) + (1u << 18) + (3u << 19));
    unsigned short* Wi3 = (unsigned short*)(ws + (3u << 20) + (1u << 18) + (6u << 19));
    char*           spk = ws + (3u << 20) + (1u << 18) + (9u << 19);
    float* out = (float*)d_out;

    hipLaunchKernelGGL(k_colmax, dim3(1024), dim3(256), 0, stream, W_rec, t1a);
    hipLaunchKernelGGL(k_packq, dim3(4096), dim3(256), 0, stream, W_rec, t1a, WrQ);
    hipLaunchKernelGGL(k_pack3, dim3(3072), dim3(256), 0, stream, W_in, Wi1, Wi2, Wi3, 768);

    void* args[] = {(void*)&fused, (void*)&Wi1, (void*)&Wi2, (void*)&Wi3, (void*)&b_in,
                    (void*)&WrQ, (void*)&t1a, (void*)&b_rec, (void*)&rdec, (void*)&rfrq,
                    (void*)&W_out, (void*)&b_out, (void*)&spk, (void*)&out};
    hipLaunchCooperativeKernel((void*)k_main, dim3(256), dim3(512), args, 0, stream);
}